// Round 16
// baseline (163.800 us; speedup 1.0000x reference)
//
#include <hip/hip_runtime.h>
#include <hip/hip_bf16.h>

typedef __attribute__((ext_vector_type(4))) int i32x4;

#define B_N 1024
#define D_K 512
#define C_N 100000
#define SCALE_F 64.0f
#define MARGIN_F 0.35f
#define BM 128
#define BN 256
#define BKB 128      // K-tile in BYTES per row (= 128 i8 elements)
#define NT_ 391      // ceil(100000/256)
#define MT_ 8        // 1024/128
#define WBLKS 25000  // norm_w blocks (4 rows each) in the merged prep kernel
#define MAXL 64.0f   // global logit bound: |cos|*64 <= 64 (+quant eps, harmless)
#define LOG2E 1.4426950408889634f
#define KQ2 (SCALE_F / (127.0f * 127.0f) * LOG2E)   // base-2 logit scale
#define MAXL2 (MAXL * LOG2E)

__device__ __forceinline__ float dot4(float4 a, float4 b) {
    return a.x * b.x + a.y * b.y + a.z * b.z + a.w * b.w;
}
__device__ __forceinline__ float amax4(float4 a) {
    return fmaxf(fmaxf(fabsf(a.x), fabsf(a.y)), fmaxf(fabsf(a.z), fabsf(a.w)));
}
__device__ __forceinline__ int packq(float v0, float v1, float v2, float v3, float qs) {
    int q0 = __float2int_rn(v0 * qs), q1 = __float2int_rn(v1 * qs);
    int q2 = __float2int_rn(v2 * qs), q3 = __float2int_rn(v3 * qs);
    return (q0 & 0xFF) | ((q1 & 0xFF) << 8) | ((q2 & 0xFF) << 16) | ((q3 & 0xFF) << 24);
}

// ------- kernel A (merged prep): blocks [0,25000) quantize W rows; blocks
//         [25000,25256) do norm_x->i8 + disc loss + target logit + rowsum zero -------
__global__ void prep_kernel(const float* __restrict__ x,
                            const int* __restrict__ target,
                            const float* __restrict__ ida,
                            const float* __restrict__ bmat,
                            char* __restrict__ xq,
                            float* __restrict__ sx,
                            char* __restrict__ wq,
                            float* __restrict__ sw,
                            float* __restrict__ dpart,
                            float* __restrict__ tlogit,
                            float* __restrict__ rowsum) {
    int blk = blockIdx.x;
    int wave = threadIdx.x >> 6;
    int l = threadIdx.x & 63;

    if (blk < WBLKS) {
        // ---- W path: normalize + i8 quantize one row per wave ----
        int row = blk * 4 + wave;
        const float4* rp = (const float4*)(ida + (size_t)row * D_K);
        float4 a = rp[l], b = rp[64 + l];
        float ssq = dot4(a, a) + dot4(b, b);
        float mx = fmaxf(amax4(a), amax4(b));
#pragma unroll
        for (int m = 1; m < 64; m <<= 1) {
            ssq += __shfl_xor(ssq, m);
            mx = fmaxf(mx, __shfl_xor(mx, m));
        }
        float inv = 1.0f / fmaxf(sqrtf(ssq), 1e-12f);
        float swm = fmaxf(mx * inv, 1e-12f);
        float qs = 127.0f / swm * inv;      // applied to RAW w
        int* oq = (int*)(wq + (size_t)row * D_K);
        oq[l] = packq(a.x, a.y, a.z, a.w, qs);
        oq[64 + l] = packq(b.x, b.y, b.z, b.w, qs);
        if (l == 0) sw[row] = swm;
        return;
    }

    // ---- x path: norm_x -> i8, disc loss, exact target logit, rowsum zero ----
    int row = (blk - WBLKS) * 4 + wave;
    long t = (long)target[row];
    const float4* xp = (const float4*)(x + (size_t)row * D_K);
    const float4* wp = (const float4*)(ida + (size_t)t * D_K);
    const float4* bp = (const float4*)(bmat + (size_t)t * D_K);
    float4 x0 = xp[l], x1 = xp[64 + l];
    float4 w0 = wp[l], w1 = wp[64 + l];
    float4 b0 = bp[l], b1 = bp[64 + l];
    float xssq = dot4(x0, x0) + dot4(x1, x1);
    float wssq = dot4(w0, w0) + dot4(w1, w1);
    float bssq = dot4(b0, b0) + dot4(b1, b1);
    float xmx = fmaxf(amax4(x0), amax4(x1));
#pragma unroll
    for (int m = 1; m < 64; m <<= 1) {
        xssq += __shfl_xor(xssq, m);
        wssq += __shfl_xor(wssq, m);
        bssq += __shfl_xor(bssq, m);
        xmx = fmaxf(xmx, __shfl_xor(xmx, m));
    }
    float xinv = 1.0f / fmaxf(sqrtf(xssq), 1e-12f);
    float winv = 1.0f / fmaxf(sqrtf(wssq), 1e-12f);
    float btn = sqrtf(bssq);
    float cs = fminf(btn, 0.05f) / fmaxf(btn, 1e-12f);

    // quantize normalized x to i8 with per-row scale sxm = max|x_n|
    float sxm = fmaxf(xmx * xinv, 1e-12f);
    float qs = 127.0f / sxm * xinv;     // applied to RAW x
    int* oq = (int*)(xq + (size_t)row * D_K);
    oq[l] = packq(x0.x, x0.y, x0.z, x0.w, qs);
    oq[64 + l] = packq(x1.x, x1.y, x1.z, x1.w, qs);

    float xs[8] = {x0.x, x0.y, x0.z, x0.w, x1.x, x1.y, x1.z, x1.w};
    float wv[8] = {w0.x, w0.y, w0.z, w0.w, w1.x, w1.y, w1.z, w1.w};
    float bv[8] = {b0.x, b0.y, b0.z, b0.w, b1.x, b1.y, b1.z, b1.w};
    float rss = 0.0f, dt = 0.0f;
#pragma unroll
    for (int i = 0; i < 8; ++i) {
        float xn = xs[i] * xinv;
        float wn = wv[i] * winv;
        float d = xn - wn;
        float r = d - bv[i] * cs;
        rss += r * r;
        dt += xn * wn;
    }
#pragma unroll
    for (int m = 1; m < 64; m <<= 1) {
        rss += __shfl_xor(rss, m);
        dt += __shfl_xor(dt, m);
    }
    if (l == 0) {
        sx[row] = sxm;
        dpart[row] = sqrtf(rss);
        tlogit[row] = SCALE_F * dt;
        rowsum[row] = 0.0f;     // zero before gemm's atomics (stream-ordered)
    }
}

// ------------- kernel B: i8 MFMA GEMM (16x16x64_i8), 512 threads / 8 waves,
//               DOUBLE-BUFFERED 2-phase K-pipeline (stage t+1 || compute t,
//               ONE barrier per K-tile), XCD-swizzled, XOR-swizzled LDS,
//               fixed-max base-2 sumexp epilogue -------------
// T3 minimum-2-phase recipe: staging L2 latency hides under read+MFMA; the
// single __syncthreads per tile is the "vmcnt(0); barrier" (compiler emits
// the full drain before s_barrier). Race-free: buf[cur] is only re-staged
// one full barrier after its last ds_read completed.
__global__ __launch_bounds__(512, 2) void gemm_lse_kernel(const char* __restrict__ A,
                                                          const char* __restrict__ W,
                                                          const float* __restrict__ sx,
                                                          const float* __restrict__ sw,
                                                          float* __restrict__ rowsum) {
    __shared__ char As[2][BM * BKB];   // 32 KB
    __shared__ char Bs[2][BN * BKB];   // 64 KB
    __shared__ float sxl[BM];
    __shared__ float swl[BN];
    __shared__ float rs[4][BM];

    int tid = threadIdx.x;
    int wave = tid >> 6, l = tid & 63;
    int wm = wave >> 2, wn = wave & 3;   // 2 M-waves x 4 N-waves, wave-tile 64x64

    // XCD-bijective swizzle: 3128 blocks = 8 * 391 exactly; xcd gets a contiguous
    // chunk of tile-space ordered (nt major, mt minor).
    int wgid = (blockIdx.x & 7) * NT_ + (blockIdx.x >> 3);
    int nt = wgid >> 3, mt = wgid & 7;
    int m0 = mt * BM, n0 = nt * BN;

    int srow = l >> 3;                       // row 0..7 within an 8-row staging chunk
    int scolB = ((l & 7) ^ (l >> 3)) * 16;   // pre-swizzled source byte slot (rule #21)

    // per-block scale tiles (ordered by the prologue __syncthreads)
    {
        if (tid < BN) {
            int c = n0 + tid;
            swl[tid] = (c < C_N) ? sw[c] : 0.0f;   // 0 => 2^-92 contribution, negligible
        } else if (tid < BN + BM) {
            sxl[tid - BN] = sx[m0 + tid - BN];
        }
    }

    // hoisted staging base pointers: A 16 chunks -> 2/wave; B 32 chunks -> 4/wave
    const char* aBase = A + (size_t)(m0 + wave * 16 + srow) * D_K + scolB;
    const char* bBase[4];
#pragma unroll
    for (int i = 0; i < 4; ++i) {
        int rn = n0 + wave * 32 + i * 8 + srow;
        rn = rn < C_N ? rn : C_N - 1;
        bBase[i] = W + (size_t)rn * D_K + scolB;
    }

#define GLL(SRC, DST) __builtin_amdgcn_global_load_lds(                          \
        (const __attribute__((address_space(1))) void*)(SRC),                    \
        (__attribute__((address_space(3))) void*)(DST), 16, 0, 0)
#define STG(KT, BUF) do {                                                        \
    _Pragma("unroll") for (int i_ = 0; i_ < 2; ++i_)                             \
        GLL(aBase + i_ * (8 * D_K) + (KT) * BKB,                                 \
            &As[BUF][(wave * 16 + i_ * 8) * BKB]);                               \
    _Pragma("unroll") for (int i_ = 0; i_ < 4; ++i_)                             \
        GLL(bBase[i_] + (KT) * BKB,                                              \
            &Bs[BUF][(wave * 32 + i_ * 8) * BKB]); } while (0)

    i32x4 acc[4][4];
#pragma unroll
    for (int i = 0; i < 4; ++i)
#pragma unroll
        for (int j = 0; j < 4; ++j) acc[i][j] = (i32x4){0, 0, 0, 0};

    int cl = l & 15, hi = l >> 4;

#define COMP(BUF) do {                                                           \
    _Pragma("unroll") for (int kk = 0; kk < 2; ++kk) {                           \
        int px = (((kk << 2) | hi) ^ (cl & 7)) * 16;                             \
        i32x4 af[4], bfr[4];                                                     \
        _Pragma("unroll") for (int mi = 0; mi < 4; ++mi)                         \
            af[mi] = *(const i32x4*)&As[BUF][(wm * 64 + mi * 16 + cl) * BKB + px]; \
        _Pragma("unroll") for (int ni = 0; ni < 4; ++ni)                         \
            bfr[ni] = *(const i32x4*)&Bs[BUF][(wn * 64 + ni * 16 + cl) * BKB + px]; \
        _Pragma("unroll") for (int mi = 0; mi < 4; ++mi)                         \
            _Pragma("unroll") for (int ni = 0; ni < 4; ++ni)                     \
                acc[mi][ni] = __builtin_amdgcn_mfma_i32_16x16x64_i8(af[mi], bfr[ni], acc[mi][ni], 0, 0, 0); \
    } } while (0)

    // prologue: stage tile 0 -> buf0; full drain + barrier
    STG(0, 0);
    __syncthreads();
    // 2-phase pipeline: stage(t+1) || compute(t); one barrier per tile
    STG(1, 1); COMP(0); __syncthreads();
    STG(2, 0); COMP(1); __syncthreads();
    STG(3, 1); COMP(0); __syncthreads();
    COMP(1);

    // epilogue: base-2 logit = acc * (sx_row*KQ2) * sw_col; per-row sum exp2(y - 64*log2e)
    float fcv[4];
#pragma unroll
    for (int ni = 0; ni < 4; ++ni)
        fcv[ni] = swl[wn * 64 + ni * 16 + cl];

#pragma unroll
    for (int mi = 0; mi < 4; ++mi) {
#pragma unroll
        for (int j = 0; j < 4; ++j) {
            float fr = sxl[wm * 64 + mi * 16 + hi * 4 + j] * KQ2;
            float se = 0.0f;
#pragma unroll
            for (int ni = 0; ni < 4; ++ni)
                se += exp2f((float)acc[mi][ni][j] * fr * fcv[ni] - MAXL2);
#pragma unroll
            for (int xm = 1; xm < 16; xm <<= 1) se += __shfl_xor(se, xm);
            if (cl == 0) rs[wn][wm * 64 + mi * 16 + hi * 4 + j] = se;
        }
    }
    __syncthreads();
    if (tid < BM) {
        float s = rs[0][tid] + rs[1][tid] + rs[2][tid] + rs[3][tid];
        atomicAdd(&rowsum[m0 + tid], s);
    }
#undef GLL
#undef STG
#undef COMP
}

// ------------- kernel C: merged row-finalize + disc reduce + scalar output -------------
__global__ void rowfin_final_kernel(const float* __restrict__ rowsum,
                                    const float* __restrict__ tlogit,
                                    const float* __restrict__ dpart,
                                    float* __restrict__ out) {
    __shared__ float redn[16];
    __shared__ float redd[16];
    int tid = threadIdx.x;          // == row, 0..1023
    float lse = MAXL + logf(rowsum[tid]);
    float st = tlogit[tid];
    // replace exp(st) by exp(st - 64*margin) inside the lse
    float corr = __expf(st - lse) * (__expf(-SCALE_F * MARGIN_F) - 1.0f);
    float lse2 = lse + log1pf(corr);
    float nll = lse2 - (st - SCALE_F * MARGIN_F);
    float dv = dpart[tid];
#pragma unroll
    for (int xm = 1; xm < 64; xm <<= 1) {
        nll += __shfl_xor(nll, xm);
        dv += __shfl_xor(dv, xm);
    }
    if ((tid & 63) == 0) {
        redn[tid >> 6] = nll;
        redd[tid >> 6] = dv;
    }
    __syncthreads();
    if (tid == 0) {
        float sn = 0.0f, sd = 0.0f;
#pragma unroll
        for (int i = 0; i < 16; ++i) { sn += redn[i]; sd += redd[i]; }
        float logp = sn * (1.0f / B_N);
        float disc = sd * (1.0f / B_N);
        float p = __expf(-logp);
        float om = 1.0f - p;
        out[0] = 0.4f * disc + om * om * logp;
    }
}

extern "C" void kernel_launch(void* const* d_in, const int* in_sizes, int n_in,
                              void* d_out, int out_size, void* d_ws, size_t ws_size,
                              hipStream_t stream) {
    const float* x = (const float*)d_in[0];
    const int* target = (const int*)d_in[1];
    const float* ida = (const float*)d_in[2];
    const float* bmat = (const float*)d_in[3];
    float* out = (float*)d_out;

    char* ws = (char*)d_ws;
    size_t off = 0;
    float* rowsum = (float*)(ws + off);  off += (size_t)B_N * 4;         // 4 KB
    char* xq = (char*)(ws + off);        off += (size_t)B_N * D_K;       // 0.5 MB
    char* wq = (char*)(ws + off);        off += (size_t)C_N * D_K;       // 51.2 MB
    float* sx = (float*)(ws + off);      off += (size_t)B_N * 4;
    float* sw = (float*)(ws + off);      off += (size_t)C_N * 4;         // 0.4 MB
    float* tlogit = (float*)(ws + off);  off += (size_t)B_N * 4;
    float* dpart = (float*)(ws + off);   off += (size_t)B_N * 4;

    prep_kernel<<<WBLKS + B_N / 4, 256, 0, stream>>>(x, target, ida, bmat, xq, sx,
                                                     wq, sw, dpart, tlogit, rowsum);
    gemm_lse_kernel<<<MT_ * NT_, 512, 0, stream>>>(xq, wq, sx, sw, rowsum);
    rowfin_final_kernel<<<1, 1024, 0, stream>>>(rowsum, tlogit, dpart, out);
}

// Round 17
// 134.403 us; speedup vs baseline: 1.2187x; 1.2187x over previous
//
#include <hip/hip_runtime.h>
#include <hip/hip_bf16.h>

typedef __attribute__((ext_vector_type(4))) int i32x4;

#define B_N 1024
#define D_K 512
#define C_N 100000
#define SCALE_F 64.0f
#define MARGIN_F 0.35f
#define BM 128
#define BN 256
#define BKB 128      // K-tile in BYTES per row (= 128 i8 elements)
#define NT_ 391      // ceil(100000/256)
#define MT_ 8        // 1024/128
#define WBLKS 25000  // norm_w blocks (4 rows each) in the merged prep kernel
#define MAXL 64.0f   // global logit bound: |cos|*64 <= 64 (+quant eps, harmless)
#define LOG2E 1.4426950408889634f
#define KQ2 (SCALE_F / (127.0f * 127.0f) * LOG2E)   // base-2 logit scale
#define MAXL2 (MAXL * LOG2E)

__device__ __forceinline__ float dot4(float4 a, float4 b) {
    return a.x * b.x + a.y * b.y + a.z * b.z + a.w * b.w;
}
__device__ __forceinline__ float amax4(float4 a) {
    return fmaxf(fmaxf(fabsf(a.x), fabsf(a.y)), fmaxf(fabsf(a.z), fabsf(a.w)));
}
__device__ __forceinline__ int packq(float v0, float v1, float v2, float v3, float qs) {
    int q0 = __float2int_rn(v0 * qs), q1 = __float2int_rn(v1 * qs);
    int q2 = __float2int_rn(v2 * qs), q3 = __float2int_rn(v3 * qs);
    return (q0 & 0xFF) | ((q1 & 0xFF) << 8) | ((q2 & 0xFF) << 16) | ((q3 & 0xFF) << 24);
}

// ------- kernel A (merged prep): blocks [0,25000) quantize W rows; blocks
//         [25000,25256) do norm_x->i8 + disc loss + target logit + rowsum zero -------
__global__ void prep_kernel(const float* __restrict__ x,
                            const int* __restrict__ target,
                            const float* __restrict__ ida,
                            const float* __restrict__ bmat,
                            char* __restrict__ xq,
                            float* __restrict__ sx,
                            char* __restrict__ wq,
                            float* __restrict__ sw,
                            float* __restrict__ dpart,
                            float* __restrict__ tlogit,
                            float* __restrict__ rowsum) {
    int blk = blockIdx.x;
    int wave = threadIdx.x >> 6;
    int l = threadIdx.x & 63;

    if (blk < WBLKS) {
        // ---- W path: normalize + i8 quantize one row per wave ----
        int row = blk * 4 + wave;
        const float4* rp = (const float4*)(ida + (size_t)row * D_K);
        float4 a = rp[l], b = rp[64 + l];
        float ssq = dot4(a, a) + dot4(b, b);
        float mx = fmaxf(amax4(a), amax4(b));
#pragma unroll
        for (int m = 1; m < 64; m <<= 1) {
            ssq += __shfl_xor(ssq, m);
            mx = fmaxf(mx, __shfl_xor(mx, m));
        }
        float inv = 1.0f / fmaxf(sqrtf(ssq), 1e-12f);
        float swm = fmaxf(mx * inv, 1e-12f);
        float qs = 127.0f / swm * inv;      // applied to RAW w
        int* oq = (int*)(wq + (size_t)row * D_K);
        oq[l] = packq(a.x, a.y, a.z, a.w, qs);
        oq[64 + l] = packq(b.x, b.y, b.z, b.w, qs);
        if (l == 0) sw[row] = swm;
        return;
    }

    // ---- x path: norm_x -> i8, disc loss, exact target logit, rowsum zero ----
    int row = (blk - WBLKS) * 4 + wave;
    long t = (long)target[row];
    const float4* xp = (const float4*)(x + (size_t)row * D_K);
    const float4* wp = (const float4*)(ida + (size_t)t * D_K);
    const float4* bp = (const float4*)(bmat + (size_t)t * D_K);
    float4 x0 = xp[l], x1 = xp[64 + l];
    float4 w0 = wp[l], w1 = wp[64 + l];
    float4 b0 = bp[l], b1 = bp[64 + l];
    float xssq = dot4(x0, x0) + dot4(x1, x1);
    float wssq = dot4(w0, w0) + dot4(w1, w1);
    float bssq = dot4(b0, b0) + dot4(b1, b1);
    float xmx = fmaxf(amax4(x0), amax4(x1));
#pragma unroll
    for (int m = 1; m < 64; m <<= 1) {
        xssq += __shfl_xor(xssq, m);
        wssq += __shfl_xor(wssq, m);
        bssq += __shfl_xor(bssq, m);
        xmx = fmaxf(xmx, __shfl_xor(xmx, m));
    }
    float xinv = 1.0f / fmaxf(sqrtf(xssq), 1e-12f);
    float winv = 1.0f / fmaxf(sqrtf(wssq), 1e-12f);
    float btn = sqrtf(bssq);
    float cs = fminf(btn, 0.05f) / fmaxf(btn, 1e-12f);

    // quantize normalized x to i8 with per-row scale sxm = max|x_n|
    float sxm = fmaxf(xmx * xinv, 1e-12f);
    float qs = 127.0f / sxm * xinv;     // applied to RAW x
    int* oq = (int*)(xq + (size_t)row * D_K);
    oq[l] = packq(x0.x, x0.y, x0.z, x0.w, qs);
    oq[64 + l] = packq(x1.x, x1.y, x1.z, x1.w, qs);

    float xs[8] = {x0.x, x0.y, x0.z, x0.w, x1.x, x1.y, x1.z, x1.w};
    float wv[8] = {w0.x, w0.y, w0.z, w0.w, w1.x, w1.y, w1.z, w1.w};
    float bv[8] = {b0.x, b0.y, b0.z, b0.w, b1.x, b1.y, b1.z, b1.w};
    float rss = 0.0f, dt = 0.0f;
#pragma unroll
    for (int i = 0; i < 8; ++i) {
        float xn = xs[i] * xinv;
        float wn = wv[i] * winv;
        float d = xn - wn;
        float r = d - bv[i] * cs;
        rss += r * r;
        dt += xn * wn;
    }
#pragma unroll
    for (int m = 1; m < 64; m <<= 1) {
        rss += __shfl_xor(rss, m);
        dt += __shfl_xor(dt, m);
    }
    if (l == 0) {
        sx[row] = sxm;
        dpart[row] = sqrtf(rss);
        tlogit[row] = SCALE_F * dt;
        rowsum[row] = 0.0f;     // zero before gemm's atomics (stream-ordered)
    }
}

// ------------- kernel B: i8 MFMA GEMM (16x16x64_i8), 512 threads / 8 waves,
//               wave-tile 64x64 (acc 4x4), XCD-swizzled, XOR-swizzled LDS,
//               fixed-max base-2 sumexp epilogue -------------
// Measured-best structure (R15, 134.4 us total): single-buffered LDS at
// 2 blocks/CU. Dbuf/deep-pipeline variants all regressed (R6/R7/R16) —
// cross-block TLP beats intra-block prefetch on this 4-K-tile-deep GEMM.
__global__ __launch_bounds__(512, 4) void gemm_lse_kernel(const char* __restrict__ A,
                                                          const char* __restrict__ W,
                                                          const float* __restrict__ sx,
                                                          const float* __restrict__ sw,
                                                          float* __restrict__ rowsum) {
    __shared__ char As[BM * BKB];   // 16 KB
    __shared__ char Bs[BN * BKB];   // 32 KB
    __shared__ float sxl[BM];
    __shared__ float swl[BN];
    __shared__ float rs[4][BM];

    int tid = threadIdx.x;
    int wave = tid >> 6, l = tid & 63;
    int wm = wave >> 2, wn = wave & 3;   // 2 M-waves x 4 N-waves, wave-tile 64x64

    // XCD-bijective swizzle: 3128 blocks = 8 * 391 exactly; xcd gets a contiguous
    // chunk of tile-space ordered (nt major, mt minor).
    int wgid = (blockIdx.x & 7) * NT_ + (blockIdx.x >> 3);
    int nt = wgid >> 3, mt = wgid & 7;
    int m0 = mt * BM, n0 = nt * BN;

    int srow = l >> 3;                       // row 0..7 within an 8-row staging chunk
    int scolB = ((l & 7) ^ (l >> 3)) * 16;   // pre-swizzled source byte slot (rule #21)

    // per-block scale tiles (ordered by the first __syncthreads below)
    {
        if (tid < BN) {
            int c = n0 + tid;
            swl[tid] = (c < C_N) ? sw[c] : 0.0f;   // 0 => 2^-92 contribution, negligible
        } else if (tid < BN + BM) {
            sxl[tid - BN] = sx[m0 + tid - BN];
        }
    }

    // hoisted staging base pointers: A 16 chunks -> 2/wave; B 32 chunks -> 4/wave
    const char* aBase = A + (size_t)(m0 + wave * 16 + srow) * D_K + scolB;
    const char* bBase[4];
#pragma unroll
    for (int i = 0; i < 4; ++i) {
        int rn = n0 + wave * 32 + i * 8 + srow;
        rn = rn < C_N ? rn : C_N - 1;
        bBase[i] = W + (size_t)rn * D_K + scolB;
    }

    i32x4 acc[4][4];
#pragma unroll
    for (int i = 0; i < 4; ++i)
#pragma unroll
        for (int j = 0; j < 4; ++j) acc[i][j] = (i32x4){0, 0, 0, 0};

    int cl = l & 15, hi = l >> 4;

#pragma unroll
    for (int kt = 0; kt < 4; ++kt) {         // 4 K-tiles of 128 i8 (fully unrolled)
#pragma unroll
        for (int i = 0; i < 2; ++i)          // A: 128 rows = 2 chunks/wave
            __builtin_amdgcn_global_load_lds(
                (const __attribute__((address_space(1))) void*)(aBase + i * (8 * D_K) + kt * BKB),
                (__attribute__((address_space(3))) void*)&As[(wave * 16 + i * 8) * BKB], 16, 0, 0);
#pragma unroll
        for (int i = 0; i < 4; ++i)          // B: 256 rows = 4 chunks/wave
            __builtin_amdgcn_global_load_lds(
                (const __attribute__((address_space(1))) void*)(bBase[i] + kt * BKB),
                (__attribute__((address_space(3))) void*)&Bs[(wave * 32 + i * 8) * BKB], 16, 0, 0);
        __syncthreads();

#pragma unroll
        for (int kk = 0; kk < 2; ++kk) {
            // physical slot = logical slot (kk*4+hi) XOR (row&7); row&7 == cl&7
            int px = (((kk << 2) | hi) ^ (cl & 7)) * 16;
            i32x4 af[4], bfr[4];
#pragma unroll
            for (int mi = 0; mi < 4; ++mi)
                af[mi] = *(const i32x4*)&As[(wm * 64 + mi * 16 + cl) * BKB + px];
#pragma unroll
            for (int ni = 0; ni < 4; ++ni)
                bfr[ni] = *(const i32x4*)&Bs[(wn * 64 + ni * 16 + cl) * BKB + px];
#pragma unroll
            for (int mi = 0; mi < 4; ++mi)
#pragma unroll
                for (int ni = 0; ni < 4; ++ni)
                    acc[mi][ni] = __builtin_amdgcn_mfma_i32_16x16x64_i8(af[mi], bfr[ni], acc[mi][ni], 0, 0, 0);
        }
        __syncthreads();
    }

    // epilogue: base-2 logit = acc * (sx_row*KQ2) * sw_col; per-row sum exp2(y - 64*log2e)
    float fcv[4];
#pragma unroll
    for (int ni = 0; ni < 4; ++ni)
        fcv[ni] = swl[wn * 64 + ni * 16 + cl];

#pragma unroll
    for (int mi = 0; mi < 4; ++mi) {
#pragma unroll
        for (int j = 0; j < 4; ++j) {
            float fr = sxl[wm * 64 + mi * 16 + hi * 4 + j] * KQ2;
            float se = 0.0f;
#pragma unroll
            for (int ni = 0; ni < 4; ++ni)
                se += exp2f((float)acc[mi][ni][j] * fr * fcv[ni] - MAXL2);
#pragma unroll
            for (int xm = 1; xm < 16; xm <<= 1) se += __shfl_xor(se, xm);
            if (cl == 0) rs[wn][wm * 64 + mi * 16 + hi * 4 + j] = se;
        }
    }
    __syncthreads();
    if (tid < BM) {
        float s = rs[0][tid] + rs[1][tid] + rs[2][tid] + rs[3][tid];
        atomicAdd(&rowsum[m0 + tid], s);
    }
}

// ------------- kernel C: merged row-finalize + disc reduce + scalar output -------------
__global__ void rowfin_final_kernel(const float* __restrict__ rowsum,
                                    const float* __restrict__ tlogit,
                                    const float* __restrict__ dpart,
                                    float* __restrict__ out) {
    __shared__ float redn[16];
    __shared__ float redd[16];
    int tid = threadIdx.x;          // == row, 0..1023
    float lse = MAXL + logf(rowsum[tid]);
    float st = tlogit[tid];
    // replace exp(st) by exp(st - 64*margin) inside the lse
    float corr = __expf(st - lse) * (__expf(-SCALE_F * MARGIN_F) - 1.0f);
    float lse2 = lse + log1pf(corr);
    float nll = lse2 - (st - SCALE_F * MARGIN_F);
    float dv = dpart[tid];
#pragma unroll
    for (int xm = 1; xm < 64; xm <<= 1) {
        nll += __shfl_xor(nll, xm);
        dv += __shfl_xor(dv, xm);
    }
    if ((tid & 63) == 0) {
        redn[tid >> 6] = nll;
        redd[tid >> 6] = dv;
    }
    __syncthreads();
    if (tid == 0) {
        float sn = 0.0f, sd = 0.0f;
#pragma unroll
        for (int i = 0; i < 16; ++i) { sn += redn[i]; sd += redd[i]; }
        float logp = sn * (1.0f / B_N);
        float disc = sd * (1.0f / B_N);
        float p = __expf(-logp);
        float om = 1.0f - p;
        out[0] = 0.4f * disc + om * om * logp;
    }
}

extern "C" void kernel_launch(void* const* d_in, const int* in_sizes, int n_in,
                              void* d_out, int out_size, void* d_ws, size_t ws_size,
                              hipStream_t stream) {
    const float* x = (const float*)d_in[0];
    const int* target = (const int*)d_in[1];
    const float* ida = (const float*)d_in[2];
    const float* bmat = (const float*)d_in[3];
    float* out = (float*)d_out;

    char* ws = (char*)d_ws;
    size_t off = 0;
    float* rowsum = (float*)(ws + off);  off += (size_t)B_N * 4;         // 4 KB
    char* xq = (char*)(ws + off);        off += (size_t)B_N * D_K;       // 0.5 MB
    char* wq = (char*)(ws + off);        off += (size_t)C_N * D_K;       // 51.2 MB
    float* sx = (float*)(ws + off);      off += (size_t)B_N * 4;
    float* sw = (float*)(ws + off);      off += (size_t)C_N * 4;         // 0.4 MB
    float* tlogit = (float*)(ws + off);  off += (size_t)B_N * 4;
    float* dpart = (float*)(ws + off);   off += (size_t)B_N * 4;

    prep_kernel<<<WBLKS + B_N / 4, 256, 0, stream>>>(x, target, ida, bmat, xq, sx,
                                                     wq, sw, dpart, tlogit, rowsum);
    gemm_lse_kernel<<<MT_ * NT_, 512, 0, stream>>>(xq, wq, sx, sw, rowsum);
    rowfin_final_kernel<<<1, 1024, 0, stream>>>(rowsum, tlogit, dpart, out);
}